// Round 12
// baseline (857.306 us; speedup 1.0000x reference)
//
#include <hip/hip_runtime.h>

#define TLEN  512
#define HID   128
#define PSLOT 16   // ring slots (each slot = 2 entries = 8 KB)

typedef __attribute__((ext_vector_type(8))) short          bf16x8;
typedef __attribute__((ext_vector_type(4))) float          f32x4;
typedef __attribute__((ext_vector_type(4))) unsigned short u16x4;
typedef unsigned long long u64;
typedef __attribute__((ext_vector_type(2))) unsigned long long u64x2;

#define LOG2E  1.4426950408889634f
#define LOG2E2 2.8853900817779268f

// RNE (cold paths)
__device__ __forceinline__ unsigned short f2bf(float f) {
    union { float f; unsigned u; } v; v.f = f;
    unsigned r = v.u + 0x7fffu + ((v.u >> 16) & 1u);
    return (unsigned short)(r >> 16);
}
// round-half-up (hot path: h)
__device__ __forceinline__ unsigned short f2bf_fast(float f) {
    union { float f; unsigned u; } v; v.f = f;
    return (unsigned short)((v.u + 0x8000u) >> 16);
}

__device__ __forceinline__ float sig_ps(float xs) {
    return __builtin_amdgcn_rcpf(1.0f + __builtin_exp2f(-xs));
}
__device__ __forceinline__ float tanh_ps(float xs) {
    return 2.0f * __builtin_amdgcn_rcpf(1.0f + __builtin_exp2f(-xs)) - 1.0f;
}

// Loads AGENT scope (L1-bypass -> same-XCD L2); stores plain/workgroup
// (dirty in local L2). Same-XCD placement proven R9/R10.
__device__ __forceinline__ int flag_peek(const int* f) {
    return __hip_atomic_load(f, __ATOMIC_RELAXED, __HIP_MEMORY_SCOPE_AGENT);
}
__device__ __forceinline__ int flag_spin(const int* f, int v) {
    int x = flag_peek(f);
    while (x < v) { __builtin_amdgcn_s_sleep(1); x = flag_peek(f); }
    return x;
}
__device__ __forceinline__ void flag_pub(int* f, int v) {
    __hip_atomic_store(f, v, __ATOMIC_RELAXED, __HIP_MEMORY_SCOPE_WORKGROUP);
}
__device__ __forceinline__ u64 ring_ld(const u64* p) {
    return __hip_atomic_load(p, __ATOMIC_RELAXED, __HIP_MEMORY_SCOPE_AGENT);
}

// Pair-ring: slot p holds entries {2p,2p+1}; u64 layout [p][tid][2].
// pin/pout flags count PAIRS; cin/cout count ENTRIES.
// Producer (even step t>=2): pair (t-2)/2 = {h(t-2),h(t-1)} read from hbuf
// (each wave reads exactly the columns it wrote -> race-free), one 16B store.
// Consumer: commit entry t+2 per step from reg queue; load pair {t+6,t+7}
// on even steps; q depth 5.
template<int MODE, bool CONS, bool PROD, bool WFC>
__device__ __forceinline__ void run_layer_p(
    const float* __restrict__ xin,
    const u64* __restrict__ rin, u64* __restrict__ rout,
    const int* pin_flag, int* cout_flag, const int* cin_flag, int* pout_flag,
    const float* __restrict__ wih, const float* __restrict__ whh,
    const float* __restrict__ bih, const float* __restrict__ bhh,
    unsigned short (* __restrict__ hbuf)[2048],
    unsigned short (* __restrict__ xbuf)[2048],
    float* __restrict__ fcred,
    const int tid, const int wave, const int lane,
    const int n16, const int quad, const int bbase)
{
    constexpr int NKTX = MODE ? 4 : 1;    // x K-tiles of 32
    constexpr int DINL = MODE ? 128 : 6;  // real input features

    // ---- weights -> register B fragments (prescaled) ----
    bf16x8 Wfx[4][NKTX], Wfh[4][4];
    f32x4  bbreg[4];   // persistent bias C-operand (never overwritten)
#pragma unroll
    for (int g = 0; g < 4; ++g) {
        const float sc = (g == 2) ? LOG2E2 : LOG2E;
        const int row = g * 128 + wave * 16 + n16;
        const float b = (bih[row] + bhh[row]) * sc;
        f32x4 bi = {b, b, b, b};
        bbreg[g] = bi;
#pragma unroll
        for (int kt = 0; kt < NKTX; ++kt) {
            bf16x8 wv;
#pragma unroll
            for (int j = 0; j < 8; ++j) {
                const int k = kt * 32 + quad * 8 + j;
                wv[j] = (short)f2bf(((k < DINL) ? wih[row * DINL + k] : 0.0f) * sc);
            }
            Wfx[g][kt] = wv;
        }
#pragma unroll
        for (int kt = 0; kt < 4; ++kt) {
            bf16x8 wv;
#pragma unroll
            for (int j = 0; j < 8; ++j) {
                const int k = kt * 32 + quad * 8 + j;
                wv[j] = (short)f2bf(whh[row * HID + k] * sc);
            }
            Wfh[g][kt] = wv;
        }
    }

    // ---- prologue ----
    { u16x4 z = {0, 0, 0, 0}; *(u16x4*)&hbuf[0][tid * 4] = z; }   // h(-1)=0
    u64 q0 = 0, q1 = 0, q2 = 0, q3 = 0, q4 = 0, qn0 = 0, qn1 = 0;
    float pfx0 = 0.0f;
    int pend = 0, cpend = 0;
    const int xm = tid >> 5, xk = tid & 31;   // MODE0 commit map
    if constexpr (CONS) {
        flag_spin(pin_flag, 1);               // pair 0 -> xbuf[0], xbuf[1]
        *(u64*)&xbuf[0][tid * 4] = ring_ld(rin + tid * 2);
        *(u64*)&xbuf[1][tid * 4] = ring_ld(rin + tid * 2 + 1);
        pend = flag_spin(pin_flag, 3);        // pairs 1,2 -> q0..q3 (entries 2..5)
        q0 = ring_ld(rin + 1 * 1024 + tid * 2);
        q1 = ring_ld(rin + 1 * 1024 + tid * 2 + 1);
        q2 = ring_ld(rin + 2 * 1024 + tid * 2);
        q3 = ring_ld(rin + 2 * 1024 + tid * 2 + 1);
    } else {
        const int ei = ((xk >> 3) * 16 + xm) * 8 + (xk & 7);
        float v0 = (xk < DINL) ? xin[((bbase + xm) * TLEN + 0) * DINL + xk] : 0.0f;
        float v1 = (xk < DINL) ? xin[((bbase + xm) * TLEN + 1) * DINL + xk] : 0.0f;
        xbuf[0][ei] = f2bf(v0);
        xbuf[1][ei] = f2bf(v1);
        if (xk < DINL) pfx0 = xin[((bbase + xm) * TLEN + 2) * DINL + xk];
    }
    if constexpr (PROD) cpend = -(1 << 30);
    __syncthreads();   // xbuf[0..1], hbuf[0] visible

    // xacc(0) = bias + x(0)@Wx  (C = bbreg on first kt)
    f32x4 accA[4], accB[4];
#pragma unroll
    for (int kt = 0; kt < NKTX; ++kt) {
        bf16x8 a = *(const bf16x8*)&xbuf[0][kt * 512 + lane * 8];
#pragma unroll
        for (int g = 0; g < 4; ++g)
            accA[g] = __builtin_amdgcn_mfma_f32_16x16x32_bf16(
                a, Wfx[g][kt], kt == 0 ? bbreg[g] : accA[g], 0, 0, 0);
    }

    float cst[4] = {0.f, 0.f, 0.f, 0.f};
    int rd = 1, wr = 2;

    // one step; PAR=0 even (ring load + pair store), PAR=1 odd (queue append)
    auto step = [&](f32x4 (&accC)[4], f32x4 (&accN)[4], int t, int PAR) {
        const int cur = t & 1, nxt = cur ^ 1;
        __syncthreads();   // hbuf[cur], xbuf[rd] ready; all vmem drained

        if (PAR == 0) {
            // ---- even: ring pair load {t+6,t+7} ----
            if constexpr (CONS) {
                if (t + 6 < TLEN) {
                    const int need = (t + 8) >> 1;
                    if (pend < need) pend = flag_spin(pin_flag, need);   // rare
                    const u64* rp = rin + (((t + 6) >> 1) & (PSLOT - 1)) * 1024 + tid * 2;
                    qn0 = ring_ld(rp);
                    qn1 = ring_ld(rp + 1);
                    pend = flag_peek(pin_flag);   // deferred refresh
                }
                if (tid == 0 && (t & 3) == 0) flag_pub(cout_flag, t + 6);
            }
            // ---- even: producer pair store {h(t-2),h(t-1)} ----
            if constexpr (PROD) {
                if (tid == 0 && t >= 4) flag_pub(pout_flag, (t - 2) >> 1);
                if (t >= 2) {
                    if (t >= 34 && cpend < t - 33) cpend = flag_spin(cin_flag, t - 33);
                    u64x2 hv;
                    hv.x = *(const u64*)&hbuf[nxt][tid * 4];   // h(t-2)
                    hv.y = *(const u64*)&hbuf[cur][tid * 4];   // h(t-1)
                    *(u64x2*)(rout + ((((t - 2) >> 1) & (PSLOT - 1)) * 1024 + tid * 2)) = hv;
                    if ((t & 3) == 2) cpend = flag_peek(cin_flag);   // deferred refresh
                }
            }
        }

        // ---- shadow: global x prefetch (MODE0) ----
        float pfx1 = 0.0f;
        if constexpr (!CONS) {
            if (t + 3 < TLEN && xk < DINL)
                pfx1 = xin[((bbase + xm) * TLEN + (t + 3)) * DINL + xk];
        }

        // ---- CRITICAL: gates = xacc(t) + h(t-1)@W_hh ----
#pragma unroll
        for (int kt = 0; kt < 4; ++kt) {
            bf16x8 a = *(const bf16x8*)&hbuf[cur][kt * 512 + lane * 8];
#pragma unroll
            for (int g = 0; g < 4; ++g)
                accC[g] = __builtin_amdgcn_mfma_f32_16x16x32_bf16(a, Wfh[g][kt], accC[g], 0, 0, 0);
        }

        // ---- cell r=0,1 ----
        unsigned short hb[4]; float hf[4];
#pragma unroll
        for (int r = 0; r < 2; ++r) {
            const float iv = sig_ps (accC[0][r]);
            const float fv = sig_ps (accC[1][r]);
            const float gv = tanh_ps(accC[2][r]);
            const float ov = sig_ps (accC[3][r]);
            const float c  = fv * cst[r] + iv * gv;
            cst[r] = c;
            const float h  = ov * tanh_ps(c * LOG2E2);
            hf[r] = h; hb[r] = f2bf_fast(h);
        }

        // ---- SHADOW x-GEMM half 1 (C = bbreg on kt 0: no init movs) ----
        const bool has_n = (t + 1 < TLEN);
        if (has_n) {
#pragma unroll
            for (int kt = 0; kt < (NKTX > 1 ? 2 : 1); ++kt) {
                bf16x8 a = *(const bf16x8*)&xbuf[rd][kt * 512 + lane * 8];
#pragma unroll
                for (int g = 0; g < 4; ++g)
                    accN[g] = __builtin_amdgcn_mfma_f32_16x16x32_bf16(
                        a, Wfx[g][kt], kt == 0 ? bbreg[g] : accN[g], 0, 0, 0);
            }
        }

        // ---- cell r=2,3 ----
#pragma unroll
        for (int r = 2; r < 4; ++r) {
            const float iv = sig_ps (accC[0][r]);
            const float fv = sig_ps (accC[1][r]);
            const float gv = tanh_ps(accC[2][r]);
            const float ov = sig_ps (accC[3][r]);
            const float c  = fv * cst[r] + iv * gv;
            cst[r] = c;
            const float h  = ov * tanh_ps(c * LOG2E2);
            hf[r] = h; hb[r] = f2bf_fast(h);
        }

        // ---- SHADOW x-GEMM half 2 ----
        if (has_n && NKTX > 1) {
#pragma unroll
            for (int kt = 2; kt < NKTX; ++kt) {
                bf16x8 a = *(const bf16x8*)&xbuf[rd][kt * 512 + lane * 8];
#pragma unroll
                for (int g = 0; g < 4; ++g)
                    accN[g] = __builtin_amdgcn_mfma_f32_16x16x32_bf16(a, Wfx[g][kt], accN[g], 0, 0, 0);
            }
        }

        // ---- h -> hbuf[nxt] ----
        {
            const int j  = wave * 16 + n16;
            const int eb = (j >> 5) * 512 + (((j & 31) >> 3) * 16) * 8 + ((j & 31) & 7);
#pragma unroll
            for (int r = 0; r < 4; ++r)
                hbuf[nxt][eb + (quad * 4 + r) * 8] = hb[r];
        }
        if constexpr (WFC) {
            if (t == TLEN - 1)
#pragma unroll
                for (int r = 0; r < 4; ++r)
                    fcred[(quad * 4 + r) * HID + wave * 16 + n16] = hf[r];
        }

        // ---- commit entry t+2 -> xbuf[wr]; queue maintenance ----
        if (t + 2 < TLEN) {
            if constexpr (CONS) {
                if (PAR == 1) { q3 = qn0; q4 = qn1; }   // pair landed (barrier-drained)
                *(u64*)&xbuf[wr][tid * 4] = q0;
                q0 = q1; q1 = q2; q2 = q3;
                if (PAR == 1) q3 = q4;
            } else {
                xbuf[wr][((xk >> 3) * 16 + xm) * 8 + (xk & 7)] = f2bf(pfx0);
                pfx0 = pfx1;
            }
        }
        rd = wr; wr = (wr == 2) ? 0 : wr + 1;
    };

    for (int t = 0; t < TLEN; t += 2) {
        step(accA, accB, t, 0);
        step(accB, accA, t + 1, 1);
    }

    // ---- producer epilogue: flush pair 255 = {h(T-2), h(T-1)} ----
    if constexpr (PROD) {
        __syncthreads();   // h(T-1)->hbuf[0] visible; pair 254 store drained
        if (tid == 0) flag_pub(pout_flag, (TLEN - 2) >> 1);   // 255 pairs visible
        {
            flag_spin(cin_flag, TLEN - 33);
            u64x2 hv;
            hv.x = *(const u64*)&hbuf[1][tid * 4];   // h(510)
            hv.y = *(const u64*)&hbuf[0][tid * 4];   // h(511)
            *(u64x2*)(rout + ((((TLEN - 2) >> 1) & (PSLOT - 1)) * 1024 + tid * 2)) = hv;
        }
        __syncthreads();   // drain final pair
        if (tid == 0) flag_pub(pout_flag, TLEN >> 1);
    }
}

extern "C" __global__ __launch_bounds__(512, 1)
void lstm3_pipe_kernel(const float* __restrict__ xin,
    const float* __restrict__ wih0, const float* __restrict__ whh0,
    const float* __restrict__ bih0, const float* __restrict__ bhh0,
    const float* __restrict__ wih1, const float* __restrict__ whh1,
    const float* __restrict__ bih1, const float* __restrict__ bhh1,
    const float* __restrict__ wih2, const float* __restrict__ whh2,
    const float* __restrict__ bih2, const float* __restrict__ bhh2,
    const float* __restrict__ fcw, const float* __restrict__ fcb,
    float* __restrict__ out,
    int* __restrict__ flags, u64* __restrict__ ring0, u64* __restrict__ ring1)
{
    __shared__ unsigned short hbuf[2][2048];   // 8 KB
    __shared__ unsigned short xbuf[3][2048];   // 12 KB
    __shared__ float fcred[16 * HID];          // 8 KB

    const int tid   = threadIdx.x;
    const int wave  = tid >> 6;
    const int lane  = tid & 63;
    const int n16   = lane & 15;
    const int quad  = lane >> 4;

    // bid = ((s>>3)*3 + layer)*8 + (s&7): all 3 stages of slice s on one XCD
    const int xcd    = blockIdx.x & 7;
    const int grp    = blockIdx.x >> 3;
    const int layer  = grp % 3;
    const int sgroup = grp / 3;
    const int slice  = sgroup * 8 + xcd;
    const int bbase  = slice * 16;

    u64* r0 = ring0 + (size_t)slice * (PSLOT * 1024);
    u64* r1 = ring1 + (size_t)slice * (PSLOT * 1024);
    int* prod0 = flags + (size_t)(0 * 64 + slice) * 64;
    int* prod1 = flags + (size_t)(1 * 64 + slice) * 64;
    int* cons1 = flags + (size_t)(2 * 64 + slice) * 64;
    int* cons2 = flags + (size_t)(3 * 64 + slice) * 64;

    if (layer == 0) {
        run_layer_p<0, false, true, false>(xin, nullptr, r0,
            nullptr, nullptr, cons1, prod0,
            wih0, whh0, bih0, bhh0, hbuf, xbuf, fcred, tid, wave, lane, n16, quad, bbase);
    } else if (layer == 1) {
        run_layer_p<1, true, true, false>(nullptr, r0, r1,
            prod0, cons1, cons2, prod1,
            wih1, whh1, bih1, bhh1, hbuf, xbuf, fcred, tid, wave, lane, n16, quad, bbase);
    } else {
        run_layer_p<1, true, false, true>(nullptr, r1, nullptr,
            prod1, cons2, nullptr, nullptr,
            wih2, whh2, bih2, bhh2, hbuf, xbuf, fcred, tid, wave, lane, n16, quad, bbase);
        __syncthreads();
        if (tid < 16) {
            float s = 0.0f;
#pragma unroll 8
            for (int j = 0; j < HID; ++j) s += fcw[j] * fcred[tid * HID + j];
            out[bbase + tid] = s + fcb[0];
        }
    }
}

extern "C" void kernel_launch(void* const* d_in, const int* in_sizes, int n_in,
                              void* d_out, int out_size, void* d_ws, size_t ws_size,
                              hipStream_t stream) {
    (void)in_sizes; (void)n_in; (void)out_size; (void)ws_size;
    const float* x    = (const float*)d_in[0];
    const float* wih0 = (const float*)d_in[1];
    const float* whh0 = (const float*)d_in[2];
    const float* bih0 = (const float*)d_in[3];
    const float* bhh0 = (const float*)d_in[4];
    const float* wih1 = (const float*)d_in[5];
    const float* whh1 = (const float*)d_in[6];
    const float* bih1 = (const float*)d_in[7];
    const float* bhh1 = (const float*)d_in[8];
    const float* wih2 = (const float*)d_in[9];
    const float* whh2 = (const float*)d_in[10];
    const float* bih2 = (const float*)d_in[11];
    const float* bhh2 = (const float*)d_in[12];
    const float* fcw  = (const float*)d_in[13];
    const float* fcb  = (const float*)d_in[14];
    float* out = (float*)d_out;

    // ws: flags 64 KB (poison-negative = not ready), ring0 8 MB, ring1 8 MB
    int* flags = (int*)d_ws;
    u64* ring0 = (u64*)((char*)d_ws + 65536);
    u64* ring1 = ring0 + (size_t)64 * PSLOT * 1024;

    lstm3_pipe_kernel<<<dim3(192), dim3(512), 0, stream>>>(
        x, wih0, whh0, bih0, bhh0, wih1, whh1, bih1, bhh1,
        wih2, whh2, bih2, bhh2, fcw, fcb, out, flags, ring0, ring1);
}